// Round 1
// baseline (410.886 us; speedup 1.0000x reference)
//
#include <hip/hip_runtime.h>

#define S 16
#define D 64

typedef __attribute__((ext_vector_type(8))) short bf16x8;
typedef __attribute__((ext_vector_type(4))) float f32x4;

__device__ __forceinline__ short f2bf(float f) {
    unsigned u = __float_as_uint(f);
    u += 0x7fffu + ((u >> 16) & 1u);   // RNE to bf16
    return (short)(u >> 16);
}

// ---- K_prep: transpose + bf16-convert weights for MFMA B-fragments ----
// W0T[d][k] = W0[k][d]          (64x64)
// WabT[d][e] = W1[e][d], e<128  (64x128)
// WcT[d][e]  = W1[128+e][d]     (64x64)
__global__ void k_prep(const float* __restrict__ W0, const float* __restrict__ W1,
                       unsigned short* __restrict__ W0T, unsigned short* __restrict__ WabT,
                       unsigned short* __restrict__ WcT) {
    int idx = blockIdx.x * 256 + threadIdx.x;
    if (idx < 4096) {
        int d = idx >> 6, k = idx & 63;
        W0T[d * 64 + k] = (unsigned short)f2bf(W0[k * 64 + d]);
    } else if (idx < 12288) {
        int o = idx - 4096; int d = o >> 7, e = o & 127;
        WabT[d * 128 + e] = (unsigned short)f2bf(W1[e * 64 + d]);
    } else if (idx < 16384) {
        int o = idx - 12288; int d = o >> 6, e = o & 63;
        WcT[d * 64 + e] = (unsigned short)f2bf(W1[(128 + e) * 64 + d]);
    }
}

// ---- K_counts: packed 4-bit multiplicity counts per (target tuple, source pos) ----
__global__ void k_counts(const int* __restrict__ msg_tgt, const int* __restrict__ msg_src,
                         unsigned long long* __restrict__ adjcnt, int E) {
    int m = blockIdx.x * 256 + threadIdx.x;
    if (m >= E) return;
    int t = msg_tgt[m];
    int k = msg_src[m] & (S - 1);     // blocks are 16-aligned: src%16 = source pos
    atomicAdd(&adjcnt[t], 1ull << (4 * k));
}

// ---- K_root: per-root fused lin0 + message matmul + pooled row extraction ----
// wave w handles H/Xmp columns [16w, 16w+16). No LDS, no barriers.
__global__ __launch_bounds__(256) void k_root(
    const float* __restrict__ X, const float* __restrict__ b0,
    const unsigned short* __restrict__ W0T,
    const unsigned long long* __restrict__ adjcnt,
    float* __restrict__ Xmp, float* __restrict__ X2X1)
{
    int root = blockIdx.x;
    int tid = threadIdx.x;
    int lane = tid & 63;
    int w = tid >> 6;
    int m = lane & 15;
    int q = lane >> 4;

    // stage 1: H tile = relu(X_blk @ W0 + b0)
    // A-frag: A[m][k = q*8+j]; two K=32 halves
    const float* xr = X + ((size_t)root * S + m) * D + q * 8;
    float4 xa = *(const float4*)(xr);
    float4 xb = *(const float4*)(xr + 4);
    float4 xc = *(const float4*)(xr + 32);
    float4 xd = *(const float4*)(xr + 36);
    bf16x8 a0, a1;
    a0[0] = f2bf(xa.x); a0[1] = f2bf(xa.y); a0[2] = f2bf(xa.z); a0[3] = f2bf(xa.w);
    a0[4] = f2bf(xb.x); a0[5] = f2bf(xb.y); a0[6] = f2bf(xb.z); a0[7] = f2bf(xb.w);
    a1[0] = f2bf(xc.x); a1[1] = f2bf(xc.y); a1[2] = f2bf(xc.z); a1[3] = f2bf(xc.w);
    a1[4] = f2bf(xd.x); a1[5] = f2bf(xd.y); a1[6] = f2bf(xd.z); a1[7] = f2bf(xd.w);

    // B-frag: B[k][n] loaded k-contiguous from W0T[n][k]
    const bf16x8* wrow = (const bf16x8*)(W0T + (size_t)(w * 16 + m) * D);
    bf16x8 bB0 = wrow[q];
    bf16x8 bB1 = wrow[4 + q];

    float bv = b0[w * 16 + m];
    f32x4 c = {bv, bv, bv, bv};
    c = __builtin_amdgcn_mfma_f32_16x16x32_bf16(a0, bB0, c, 0, 0, 0);
    c = __builtin_amdgcn_mfma_f32_16x16x32_bf16(a1, bB1, c, 0, 0, 0);

    float h0 = fmaxf(c[0], 0.f), h1 = fmaxf(c[1], 0.f);
    float h2 = fmaxf(c[2], 0.f), h3 = fmaxf(c[3], 0.f);

    // stage 2: Xmp tile = CNT(16x16, K padded to 32) @ H(16 x tile)
    unsigned long long cw = adjcnt[(size_t)root * S + m];
    bf16x8 A2, B2;
#pragma unroll
    for (int j = 0; j < 8; j++) {
        int k = q * 8 + j;                       // k in [0,32)
        float cv = (q < 2) ? (float)((cw >> (4 * k)) & 15ull) : 0.f;
        A2[j] = f2bf(cv);
    }
    // B2[k=8q+j][n]: H row 8q+j lives in lane (quad 2q or 2q+1, same col), reg j&3.
    int src0 = ((2 * q) * 16 + m) & 63;
    int src1 = ((2 * q + 1) * 16 + m) & 63;
    float s0 = __shfl(h0, src0), s1 = __shfl(h1, src0), s2 = __shfl(h2, src0), s3 = __shfl(h3, src0);
    float s4 = __shfl(h0, src1), s5 = __shfl(h1, src1), s6 = __shfl(h2, src1), s7 = __shfl(h3, src1);
    // rows k>=16 have A2 column == 0, so B2 content there is irrelevant
    B2[0] = f2bf(s0); B2[1] = f2bf(s1); B2[2] = f2bf(s2); B2[3] = f2bf(s3);
    B2[4] = f2bf(s4); B2[5] = f2bf(s5); B2[6] = f2bf(s6); B2[7] = f2bf(s7);

    f32x4 z4 = {0.f, 0.f, 0.f, 0.f};
    f32x4 xm = __builtin_amdgcn_mfma_f32_16x16x32_bf16(A2, B2, z4, 0, 0, 0);

    // write Xmp rows q*4+r, col w*16+m  (Xmp lives in d_out as scratch)
    float* xout = Xmp + ((size_t)root * S + q * 4) * D + w * 16 + m;
    xout[0 * D] = xm[0];
    xout[1 * D] = xm[1];
    xout[2 * D] = xm[2];
    xout[3 * D] = xm[3];

    // Psum over 16 rows (cross-quad xor reduce) and X1 = row 0
    float ps = xm[0] + xm[1] + xm[2] + xm[3];
    ps += __shfl_xor(ps, 16);
    ps += __shfl_xor(ps, 32);
    float x1 = __shfl(xm[0], m);          // lane (quad0, col m) holds row 0
    if (q == 0) {
        float* o = X2X1 + (size_t)root * 128 + w * 16 + m;
        o[0]  = ps * (1.f / 16.f);        // X2 (Pcnt == 16 exactly)
        o[64] = x1;                       // X1 (diag row j=0)
    }
}

// ---- K_qavg: windowed anti-diagonal mean over roots per node ----
__global__ __launch_bounds__(256) void k_qavg(
    const float* __restrict__ Xmp, float* __restrict__ Qavg, int R, int N)
{
    int w = threadIdx.x >> 6, d = threadIdx.x & 63;
    int n = blockIdx.x * 4 + w;
    if (n >= N) return;
    int lo = n - (S - 1); if (lo < 0) lo = 0;
    int hi = (n < R - 1) ? n : (R - 1);
    float s = 0.f;
    for (int i = lo; i <= hi; i++)
        s += Xmp[((size_t)i * (S - 1) + n) * D + d];   // tuple index 15*i + n
    Qavg[(size_t)n * D + d] = s / (float)(hi - lo + 1);
}

// ---- K_lin: Y[R,64] = [X2|X1]@W1ab + b1  and  Z[N,64] = Qavg@W1c ----
__global__ __launch_bounds__(256) void k_lin(
    const float* __restrict__ X2X1, const float* __restrict__ Qavg,
    const unsigned short* __restrict__ WabT, const unsigned short* __restrict__ WcT,
    const float* __restrict__ b1,
    float* __restrict__ Y, float* __restrict__ Z, int R, int N, int RB)
{
    int tid = threadIdx.x, lane = tid & 63, w = tid >> 6, m = lane & 15, q = lane >> 4;
    int b = blockIdx.x;
    if (b < RB) {
        int row0 = b * 16;
        const float* arow = X2X1 + (size_t)(row0 + m) * 128;
        float bv = b1[w * 16 + m];
        f32x4 c = {bv, bv, bv, bv};
        const bf16x8* brow = (const bf16x8*)(WabT + (size_t)(w * 16 + m) * 128);
#pragma unroll
        for (int kh = 0; kh < 4; kh++) {
            const float* ap = arow + kh * 32 + q * 8;
            float4 u = *(const float4*)ap, v = *(const float4*)(ap + 4);
            bf16x8 a;
            a[0] = f2bf(u.x); a[1] = f2bf(u.y); a[2] = f2bf(u.z); a[3] = f2bf(u.w);
            a[4] = f2bf(v.x); a[5] = f2bf(v.y); a[6] = f2bf(v.z); a[7] = f2bf(v.w);
            c = __builtin_amdgcn_mfma_f32_16x16x32_bf16(a, brow[kh * 4 + q], c, 0, 0, 0);
        }
#pragma unroll
        for (int r = 0; r < 4; r++) {
            int row = row0 + q * 4 + r;
            if (row < R) Y[(size_t)row * 64 + w * 16 + m] = c[r];
        }
    } else {
        int row0 = (b - RB) * 16;
        const float* arow = Qavg + (size_t)(row0 + m) * 64;
        f32x4 c = {0.f, 0.f, 0.f, 0.f};
        const bf16x8* brow = (const bf16x8*)(WcT + (size_t)(w * 16 + m) * 64);
#pragma unroll
        for (int kh = 0; kh < 2; kh++) {
            const float* ap = arow + kh * 32 + q * 8;
            float4 u = *(const float4*)ap, v = *(const float4*)(ap + 4);
            bf16x8 a;
            a[0] = f2bf(u.x); a[1] = f2bf(u.y); a[2] = f2bf(u.z); a[3] = f2bf(u.w);
            a[4] = f2bf(v.x); a[5] = f2bf(v.y); a[6] = f2bf(v.z); a[7] = f2bf(v.w);
            c = __builtin_amdgcn_mfma_f32_16x16x32_bf16(a, brow[kh * 4 + q], c, 0, 0, 0);
        }
#pragma unroll
        for (int r = 0; r < 4; r++) {
            int row = row0 + q * 4 + r;
            if (row < N) Z[(size_t)row * 64 + w * 16 + m] = c[r];
        }
    }
}

// ---- K_out: out[i*16+j] = Y[i] + Z[i+j], float4-vectorized ----
__global__ __launch_bounds__(256) void k_out(
    const float* __restrict__ Y, const float* __restrict__ Z,
    float4* __restrict__ out, int M)
{
    int idx = blockIdx.x * 256 + threadIdx.x;
    if (idx >= M * (D / 4)) return;
    int t = idx >> 4, d4 = idx & 15;
    int i = t >> 4, j = t & 15;
    int n = i + j;
    const float4* Y4 = (const float4*)Y;
    const float4* Z4 = (const float4*)Z;
    float4 a = Y4[(size_t)i * 16 + d4];
    float4 b = Z4[(size_t)n * 16 + d4];
    float4 o;
    o.x = a.x + b.x; o.y = a.y + b.y; o.z = a.z + b.z; o.w = a.w + b.w;
    out[idx] = o;
}

extern "C" void kernel_launch(void* const* d_in, const int* in_sizes, int n_in,
                              void* d_out, int out_size, void* d_ws, size_t ws_size,
                              hipStream_t stream) {
    (void)n_in; (void)out_size; (void)ws_size;
    const float* X  = (const float*)d_in[0];
    const float* W0 = (const float*)d_in[1];
    const float* b0 = (const float*)d_in[2];
    const float* W1 = (const float*)d_in[3];
    const float* b1 = (const float*)d_in[4];
    const int* msg_tgt = (const int*)d_in[8];
    const int* msg_src = (const int*)d_in[9];
    const int M = in_sizes[5];           // rootid size = R*S
    const int R = in_sizes[7];           // diag_tuple size
    const int E = in_sizes[8];           // number of tuple-level messages
    const int N = R + S - 1;             // node count (R = N-S+1)

    char* p = (char*)d_ws;
    unsigned long long* adjcnt = (unsigned long long*)p; p += (size_t)M * 8;
    float* X2X1 = (float*)p;             p += (size_t)R * 128 * 4;
    float* Qavg = (float*)p;             p += (size_t)N * 64 * 4;
    float* Y    = (float*)p;             p += (size_t)R * 64 * 4;
    float* Z    = (float*)p;             p += (size_t)N * 64 * 4;
    unsigned short* W0T  = (unsigned short*)p; p += (size_t)4096 * 2;
    unsigned short* WabT = (unsigned short*)p; p += (size_t)8192 * 2;
    unsigned short* WcT  = (unsigned short*)p; p += (size_t)4096 * 2;

    float* Xmp = (float*)d_out;          // d_out doubles as Xmp scratch (M*64 floats)

    hipMemsetAsync(adjcnt, 0, (size_t)M * 8, stream);
    k_prep<<<64, 256, 0, stream>>>(W0, W1, W0T, WabT, WcT);
    k_counts<<<(E + 255) / 256, 256, 0, stream>>>(msg_tgt, msg_src, adjcnt, E);
    k_root<<<R, 256, 0, stream>>>(X, b0, W0T, adjcnt, Xmp, X2X1);
    k_qavg<<<(N + 3) / 4, 256, 0, stream>>>(Xmp, Qavg, R, N);
    int RB = (R + 15) / 16, NB = (N + 15) / 16;
    k_lin<<<RB + NB, 256, 0, stream>>>(X2X1, Qavg, WabT, WcT, b1, Y, Z, R, N, RB);
    k_out<<<(M * (D / 4) + 255) / 256, 256, 0, stream>>>(Y, Z, (float4*)d_out, M);
}

// Round 2
// 371.300 us; speedup vs baseline: 1.1066x; 1.1066x over previous
//
#include <hip/hip_runtime.h>

#define S 16
#define D 64
#define G 16            // roots per k_root block
#define PROWS 31        // G + S - 1 node rows per group
#define PSTRIDE 66      // LDS row stride: (2*row+col)%32 -> uniform 2-way (free)

typedef __attribute__((ext_vector_type(8))) short bf16x8;
typedef __attribute__((ext_vector_type(4))) float f32x4;

union BF8 { unsigned u[4]; bf16x8 v; };

// round-half-up f32->bf16 pack, 3 VALU per 2 elements
__device__ __forceinline__ unsigned pk2bf(float x, float y) {
    unsigned ux = __float_as_uint(x) + 0x8000u;
    unsigned uy = __float_as_uint(y) + 0x8000u;
    return __builtin_amdgcn_perm(uy, ux, 0x07060302);  // {hi16(ux), hi16(uy)}
}
__device__ __forceinline__ bf16x8 pk8(float a, float b, float c, float d,
                                      float e, float f, float g, float h) {
    BF8 t;
    t.u[0] = pk2bf(a, b); t.u[1] = pk2bf(c, d);
    t.u[2] = pk2bf(e, f); t.u[3] = pk2bf(g, h);
    return t.v;
}
// RNE (one-time weight prep only)
__device__ __forceinline__ short f2bf(float f) {
    unsigned u = __float_as_uint(f);
    u += 0x7fffu + ((u >> 16) & 1u);
    return (short)(u >> 16);
}

// ---- K_prep: transpose + bf16-convert weights for MFMA B-fragments ----
__global__ void k_prep(const float* __restrict__ W0, const float* __restrict__ W1,
                       unsigned short* __restrict__ W0T, unsigned short* __restrict__ WabT,
                       unsigned short* __restrict__ WcT) {
    int idx = blockIdx.x * 256 + threadIdx.x;
    if (idx < 4096) {
        int d = idx >> 6, k = idx & 63;
        W0T[d * 64 + k] = (unsigned short)f2bf(W0[k * 64 + d]);
    } else if (idx < 12288) {
        int o = idx - 4096; int d = o >> 7, e = o & 127;
        WabT[d * 128 + e] = (unsigned short)f2bf(W1[e * 64 + d]);
    } else if (idx < 16384) {
        int o = idx - 12288; int d = o >> 6, e = o & 63;
        WcT[d * 64 + e] = (unsigned short)f2bf(W1[(128 + e) * 64 + d]);
    }
}

// ---- K_counts: packed 4-bit multiplicity per (target tuple, source pos) ----
__global__ void k_counts(const int* __restrict__ msg_tgt, const int* __restrict__ msg_src,
                         unsigned long long* __restrict__ adjcnt, int E) {
    int m = blockIdx.x * 256 + threadIdx.x;
    if (m >= E) return;
    int t = msg_tgt[m];
    int k = msg_src[m] & (S - 1);
    atomicAdd(&adjcnt[t], 1ull << (4 * k));
}

// ---- K_root: G roots per block; lin0 MFMA + CNT MFMA; Xmp never leaves the CU.
// Outputs: X2X1 per root, Qpart node-partials per group. No barriers in the loop:
// wave w exclusively owns LDS columns [16w,16w+16).
__global__ __launch_bounds__(256) void k_root(
    const float* __restrict__ X, const float* __restrict__ b0,
    const unsigned short* __restrict__ W0T,
    const unsigned long long* __restrict__ adjcnt,
    float* __restrict__ X2X1, float* __restrict__ Qpart, int R)
{
    __shared__ float part[PROWS][PSTRIDE];
    int grp = blockIdx.x;
    int tid = threadIdx.x, lane = tid & 63, w = tid >> 6, m = lane & 15, q = lane >> 4;
    int col = w * 16 + m;

    for (int r = q; r < PROWS; r += 4) part[r][col] = 0.f;   // own columns only

    const bf16x8* wrow = (const bf16x8*)(W0T + (size_t)col * D);
    bf16x8 bB0 = wrow[q], bB1 = wrow[4 + q];
    float bv = b0[col];

    int root0 = grp * G;
    int gmax = R - root0; if (gmax > G) gmax = G;
    for (int g = 0; g < gmax; g++) {
        int root = root0 + g;
        // stage 1: H = relu(X_blk @ W0 + b0)
        const float* xr = X + ((size_t)root * S + m) * D + q * 8;
        float4 xa = *(const float4*)(xr);
        float4 xb = *(const float4*)(xr + 4);
        float4 xc = *(const float4*)(xr + 32);
        float4 xd = *(const float4*)(xr + 36);
        bf16x8 a0 = pk8(xa.x, xa.y, xa.z, xa.w, xb.x, xb.y, xb.z, xb.w);
        bf16x8 a1 = pk8(xc.x, xc.y, xc.z, xc.w, xd.x, xd.y, xd.z, xd.w);

        f32x4 c = {bv, bv, bv, bv};
        c = __builtin_amdgcn_mfma_f32_16x16x32_bf16(a0, bB0, c, 0, 0, 0);
        c = __builtin_amdgcn_mfma_f32_16x16x32_bf16(a1, bB1, c, 0, 0, 0);
        float h0 = fmaxf(c[0], 0.f), h1 = fmaxf(c[1], 0.f);
        float h2 = fmaxf(c[2], 0.f), h3 = fmaxf(c[3], 0.f);

        // stage 2: Xmp tile = CNT(16x16 in K=32) @ H
        unsigned long long cw = adjcnt[(size_t)root * S + m];
        unsigned w32 = (q == 0) ? (unsigned)cw : ((q == 1) ? (unsigned)(cw >> 32) : 0u);
        float c0 = (float)((w32 >> 0) & 15u),  c1 = (float)((w32 >> 4) & 15u);
        float c2 = (float)((w32 >> 8) & 15u),  c3 = (float)((w32 >> 12) & 15u);
        float c4 = (float)((w32 >> 16) & 15u), c5 = (float)((w32 >> 20) & 15u);
        float c6 = (float)((w32 >> 24) & 15u), c7 = (float)((w32 >> 28) & 15u);
        bf16x8 A2 = pk8(c0, c1, c2, c3, c4, c5, c6, c7);

        int src0 = ((2 * q) * 16 + m) & 63;
        int src1 = ((2 * q + 1) * 16 + m) & 63;
        float s0 = __shfl(h0, src0), s1 = __shfl(h1, src0), s2 = __shfl(h2, src0), s3 = __shfl(h3, src0);
        float s4 = __shfl(h0, src1), s5 = __shfl(h1, src1), s6 = __shfl(h2, src1), s7 = __shfl(h3, src1);
        bf16x8 B2 = pk8(s0, s1, s2, s3, s4, s5, s6, s7);

        f32x4 z4 = {0.f, 0.f, 0.f, 0.f};
        f32x4 xm = __builtin_amdgcn_mfma_f32_16x16x32_bf16(A2, B2, z4, 0, 0, 0);

        // accumulate node partials: tuple row j = q*4+r -> node offset g+j
        int rb = g + q * 4;
        part[rb + 0][col] += xm[0];
        part[rb + 1][col] += xm[1];
        part[rb + 2][col] += xm[2];
        part[rb + 3][col] += xm[3];

        // X2 (block mean) + X1 (diag row 0)
        float ps = xm[0] + xm[1] + xm[2] + xm[3];
        ps += __shfl_xor(ps, 16);
        ps += __shfl_xor(ps, 32);
        float x1 = __shfl(xm[0], m);
        if (q == 0) {
            float* o = X2X1 + (size_t)root * 128 + col;
            o[0]  = ps * (1.f / 16.f);
            o[64] = x1;
        }
    }
    __syncthreads();
    float* qp = Qpart + (size_t)grp * (PROWS * 64);
    for (int idx = tid; idx < PROWS * 64; idx += 256)
        qp[idx] = part[idx >> 6][idx & 63];
}

// ---- K_lin2: Y[R,64] = [X2|X1]@W1ab + b1 ; Z[N,64] = Qavg@W1c (gathers Qpart) ----
__global__ __launch_bounds__(256) void k_lin2(
    const float* __restrict__ X2X1, const float* __restrict__ Qpart,
    const unsigned short* __restrict__ WabT, const unsigned short* __restrict__ WcT,
    const float* __restrict__ b1,
    float* __restrict__ Y, float* __restrict__ Z, int R, int N, int RB)
{
    int tid = threadIdx.x, lane = tid & 63, w = tid >> 6, m = lane & 15, q = lane >> 4;
    int b = blockIdx.x;
    if (b < RB) {
        int row0 = b * 16;
        const float* arow = X2X1 + (size_t)(row0 + m) * 128;
        float bv = b1[w * 16 + m];
        f32x4 c = {bv, bv, bv, bv};
        const bf16x8* brow = (const bf16x8*)(WabT + (size_t)(w * 16 + m) * 128);
#pragma unroll
        for (int kh = 0; kh < 4; kh++) {
            const float* ap = arow + kh * 32 + q * 8;
            float4 u = *(const float4*)ap, v = *(const float4*)(ap + 4);
            bf16x8 a = pk8(u.x, u.y, u.z, u.w, v.x, v.y, v.z, v.w);
            c = __builtin_amdgcn_mfma_f32_16x16x32_bf16(a, brow[kh * 4 + q], c, 0, 0, 0);
        }
#pragma unroll
        for (int r = 0; r < 4; r++) {
            int row = row0 + q * 4 + r;
            if (row < R) Y[(size_t)row * 64 + w * 16 + m] = c[r];
        }
    } else {
        int row0 = (b - RB) * 16;
        int n = row0 + m;
        float inv = 0.f;
        int gLo = 0, gHi = -1;
        if (n < N) {
            int lo = n - (S - 1); if (lo < 0) lo = 0;
            int hi = (n < R - 1) ? n : (R - 1);
            inv = 1.f / (float)(hi - lo + 1);
            gLo = lo >> 4; gHi = hi >> 4;
        }
        f32x4 c = {0.f, 0.f, 0.f, 0.f};
        const bf16x8* brow = (const bf16x8*)(WcT + (size_t)(w * 16 + m) * 64);
#pragma unroll
        for (int kh = 0; kh < 2; kh++) {
            int k0 = kh * 32 + q * 8;
            float4 u = {0.f, 0.f, 0.f, 0.f}, v = {0.f, 0.f, 0.f, 0.f};
            for (int g = gLo; g <= gHi; g++) {
                const float* src = Qpart + ((size_t)g * PROWS + (n - g * 16)) * 64 + k0;
                float4 uu = *(const float4*)src, vv = *(const float4*)(src + 4);
                u.x += uu.x; u.y += uu.y; u.z += uu.z; u.w += uu.w;
                v.x += vv.x; v.y += vv.y; v.z += vv.z; v.w += vv.w;
            }
            bf16x8 a = pk8(u.x * inv, u.y * inv, u.z * inv, u.w * inv,
                           v.x * inv, v.y * inv, v.z * inv, v.w * inv);
            c = __builtin_amdgcn_mfma_f32_16x16x32_bf16(a, brow[kh * 4 + q], c, 0, 0, 0);
        }
#pragma unroll
        for (int r = 0; r < 4; r++) {
            int row = row0 + q * 4 + r;
            if (row < N) Z[(size_t)row * 64 + w * 16 + m] = c[r];
        }
    }
}

// ---- K_out: out[i*16+j] = Y[i] + Z[i+j] ----
__global__ __launch_bounds__(256) void k_out(
    const float* __restrict__ Y, const float* __restrict__ Z,
    float4* __restrict__ out, int M)
{
    int idx = blockIdx.x * 256 + threadIdx.x;
    if (idx >= M * (D / 4)) return;
    int t = idx >> 4, d4 = idx & 15;
    int i = t >> 4, j = t & 15;
    int n = i + j;
    const float4* Y4 = (const float4*)Y;
    const float4* Z4 = (const float4*)Z;
    float4 a = Y4[(size_t)i * 16 + d4];
    float4 b = Z4[(size_t)n * 16 + d4];
    float4 o;
    o.x = a.x + b.x; o.y = a.y + b.y; o.z = a.z + b.z; o.w = a.w + b.w;
    out[idx] = o;
}

extern "C" void kernel_launch(void* const* d_in, const int* in_sizes, int n_in,
                              void* d_out, int out_size, void* d_ws, size_t ws_size,
                              hipStream_t stream) {
    (void)n_in; (void)out_size; (void)ws_size;
    const float* X  = (const float*)d_in[0];
    const float* W0 = (const float*)d_in[1];
    const float* b0 = (const float*)d_in[2];
    const float* W1 = (const float*)d_in[3];
    const float* b1 = (const float*)d_in[4];
    const int* msg_tgt = (const int*)d_in[8];
    const int* msg_src = (const int*)d_in[9];
    const int M = in_sizes[5];           // rootid size = R*S
    const int R = in_sizes[7];           // diag_tuple size
    const int E = in_sizes[8];           // number of tuple-level messages
    const int N = R + S - 1;

    char* p = (char*)d_ws;
    unsigned long long* adjcnt = (unsigned long long*)p; p += (size_t)M * 8;
    float* X2X1 = (float*)p;             p += (size_t)R * 128 * 4;
    float* Y    = (float*)p;             p += (size_t)R * 64 * 4;
    float* Z    = (float*)p;             p += (size_t)N * 64 * 4;
    unsigned short* W0T  = (unsigned short*)p; p += (size_t)4096 * 2;
    unsigned short* WabT = (unsigned short*)p; p += (size_t)8192 * 2;
    unsigned short* WcT  = (unsigned short*)p; p += (size_t)4096 * 2;

    // Qpart lives in d_out (written by k_root, consumed by k_lin2, then k_out
    // fully overwrites d_out). NG*31*64*4 ~ 14.9 MB << out bytes.
    int NG = (R + G - 1) / G;
    float* Qpart = (float*)d_out;

    hipMemsetAsync(adjcnt, 0, (size_t)M * 8, stream);
    k_prep<<<64, 256, 0, stream>>>(W0, W1, W0T, WabT, WcT);
    k_counts<<<(E + 255) / 256, 256, 0, stream>>>(msg_tgt, msg_src, adjcnt, E);
    k_root<<<NG, 256, 0, stream>>>(X, b0, W0T, adjcnt, X2X1, Qpart, R);
    int RB = (R + 15) / 16, NB = (N + 15) / 16;
    k_lin2<<<RB + NB, 256, 0, stream>>>(X2X1, Qpart, WabT, WcT, b1, Y, Z, R, N, RB);
    k_out<<<(M * (D / 4) + 255) / 256, 256, 0, stream>>>(Y, Z, (float4*)d_out, M);
}

// Round 3
// 345.985 us; speedup vs baseline: 1.1876x; 1.0732x over previous
//
#include <hip/hip_runtime.h>

#define S 16
#define D 64
#define G 16            // roots per k_root block (= one MFMA M-tile for Y)
#define PROWS 31        // G + S - 1 node rows per group
#define PSTR 66         // part row stride: (8q+m) pattern -> max 2-way (free)
#define XSTR 136        // x2x1 LDS row stride in bf16 (128 + 8 pad)

typedef __attribute__((ext_vector_type(8))) short bf16x8;
typedef __attribute__((ext_vector_type(4))) float f32x4;

union BF8 { unsigned u[4]; bf16x8 v; };

// round-half-up f32->bf16 pack, 3 VALU per 2 elements
__device__ __forceinline__ unsigned pk2bf(float x, float y) {
    unsigned ux = __float_as_uint(x) + 0x8000u;
    unsigned uy = __float_as_uint(y) + 0x8000u;
    return __builtin_amdgcn_perm(uy, ux, 0x07060302);  // {hi16(ux), hi16(uy)}
}
__device__ __forceinline__ bf16x8 pk8(float a, float b, float c, float d,
                                      float e, float f, float g, float h) {
    BF8 t;
    t.u[0] = pk2bf(a, b); t.u[1] = pk2bf(c, d);
    t.u[2] = pk2bf(e, f); t.u[3] = pk2bf(g, h);
    return t.v;
}
__device__ __forceinline__ unsigned short f2bf_rhu(float x) {
    return (unsigned short)((__float_as_uint(x) + 0x8000u) >> 16);
}
// RNE (one-time weight prep only)
__device__ __forceinline__ short f2bf(float f) {
    unsigned u = __float_as_uint(f);
    u += 0x7fffu + ((u >> 16) & 1u);
    return (short)(u >> 16);
}

// ---- K_prep: transpose + bf16-convert weights for MFMA B-fragments ----
__global__ void k_prep(const float* __restrict__ W0, const float* __restrict__ W1,
                       unsigned short* __restrict__ W0T, unsigned short* __restrict__ WabT,
                       unsigned short* __restrict__ WcT) {
    int idx = blockIdx.x * 256 + threadIdx.x;
    if (idx < 4096) {
        int d = idx >> 6, k = idx & 63;
        W0T[d * 64 + k] = (unsigned short)f2bf(W0[k * 64 + d]);
    } else if (idx < 12288) {
        int o = idx - 4096; int d = o >> 7, e = o & 127;
        WabT[d * 128 + e] = (unsigned short)f2bf(W1[e * 64 + d]);
    } else if (idx < 16384) {
        int o = idx - 12288; int d = o >> 6, e = o & 63;
        WcT[d * 64 + e] = (unsigned short)f2bf(W1[(128 + e) * 64 + d]);
    }
}

// ---- K_counts: packed 4-bit multiplicity per (target tuple, source pos) ----
__global__ void k_counts(const int* __restrict__ msg_tgt, const int* __restrict__ msg_src,
                         unsigned long long* __restrict__ adjcnt, int E) {
    int m = blockIdx.x * 256 + threadIdx.x;
    if (m >= E) return;
    int t = msg_tgt[m];
    int k = msg_src[m] & (S - 1);
    atomicAdd(&adjcnt[t], 1ull << (4 * k));
}

// ---- K_root v2: one WAVE per root. Per root: lin0 (8 MFMA) + CNT matmul (4 MFMA),
// node partials in per-wave private LDS, X2X1 to LDS (bf16), fused Y matmul.
__global__ __launch_bounds__(256, 4) void k_root(
    const float* __restrict__ X, const float* __restrict__ b0,
    const unsigned short* __restrict__ W0T,
    const unsigned long long* __restrict__ adjcnt,
    const unsigned short* __restrict__ WabT, const float* __restrict__ b1,
    float* __restrict__ Y, float* __restrict__ Qpart, int R)
{
    __shared__ float part[4][PROWS][PSTR];         // 32736 B, per-wave private
    __shared__ unsigned short x2x1[G][XSTR];       // 4352 B
    int grp = blockIdx.x;
    int tid = threadIdx.x, lane = tid & 63, w = tid >> 6, m = lane & 15, q = lane >> 4;

    // zero own region (cols 0..63 only; no barrier needed: private per wave)
#pragma unroll 4
    for (int r = 0; r < PROWS; r++) part[w][r][lane] = 0.f;

    // stage-1 B fragments for all 4 column groups (resident in VGPRs)
    bf16x8 bB[8];
    float bv[4];
#pragma unroll
    for (int cg = 0; cg < 4; cg++) {
        const bf16x8* wr = (const bf16x8*)(W0T + (size_t)(cg * 16 + m) * 64);
        bB[cg * 2] = wr[q]; bB[cg * 2 + 1] = wr[4 + q];
        bv[cg] = b0[cg * 16 + m];
    }

    int root0 = grp * G;
    int gmax = R - root0; if (gmax > G) gmax = G;
    const float* Xg = X + (size_t)root0 * S * D;

    float4 xa, xb, xc, xd; unsigned long long cw;
    if (w < gmax) {
        const float* xr = Xg + ((size_t)w * S + m) * D + q * 8;
        xa = *(const float4*)(xr);
        xb = *(const float4*)(xr + 4);
        xc = *(const float4*)(xr + 32);
        xd = *(const float4*)(xr + 36);
        cw = adjcnt[(size_t)(root0 + w) * S + m];
    }

    for (int g = w; g < gmax; g += 4) {
        // prefetch next root for this wave
        float4 nxa, nxb, nxc, nxd; unsigned long long ncw;
        int gn = g + 4;
        bool pf = (gn < gmax);
        if (pf) {
            const float* xr = Xg + ((size_t)gn * S + m) * D + q * 8;
            nxa = *(const float4*)(xr);
            nxb = *(const float4*)(xr + 4);
            nxc = *(const float4*)(xr + 32);
            nxd = *(const float4*)(xr + 36);
            ncw = adjcnt[(size_t)(root0 + gn) * S + m];
        }

        // stage 1: H = relu(X_blk @ W0 + b0), all 4 column groups
        bf16x8 a0 = pk8(xa.x, xa.y, xa.z, xa.w, xb.x, xb.y, xb.z, xb.w);
        bf16x8 a1 = pk8(xc.x, xc.y, xc.z, xc.w, xd.x, xd.y, xd.z, xd.w);
        f32x4 h4[4];
#pragma unroll
        for (int cg = 0; cg < 4; cg++) {
            f32x4 c = {bv[cg], bv[cg], bv[cg], bv[cg]};
            c = __builtin_amdgcn_mfma_f32_16x16x32_bf16(a0, bB[cg * 2], c, 0, 0, 0);
            c = __builtin_amdgcn_mfma_f32_16x16x32_bf16(a1, bB[cg * 2 + 1], c, 0, 0, 0);
            h4[cg][0] = fmaxf(c[0], 0.f); h4[cg][1] = fmaxf(c[1], 0.f);
            h4[cg][2] = fmaxf(c[2], 0.f); h4[cg][3] = fmaxf(c[3], 0.f);
        }

        // stage 2 A-frag: CNT row m, k = q*8+j (rows k>=16 zero)
        unsigned w32 = (q == 0) ? (unsigned)cw : ((q == 1) ? (unsigned)(cw >> 32) : 0u);
        bf16x8 A2 = pk8((float)((w32 >> 0) & 15u),  (float)((w32 >> 4) & 15u),
                        (float)((w32 >> 8) & 15u),  (float)((w32 >> 12) & 15u),
                        (float)((w32 >> 16) & 15u), (float)((w32 >> 20) & 15u),
                        (float)((w32 >> 24) & 15u), (float)((w32 >> 28) & 15u));
        int src0 = ((2 * q) * 16 + m) & 63;
        int src1 = ((2 * q + 1) * 16 + m) & 63;

#pragma unroll
        for (int cg = 0; cg < 4; cg++) {
            float s0 = __shfl(h4[cg][0], src0), s1 = __shfl(h4[cg][1], src0);
            float s2 = __shfl(h4[cg][2], src0), s3 = __shfl(h4[cg][3], src0);
            float s4 = __shfl(h4[cg][0], src1), s5 = __shfl(h4[cg][1], src1);
            float s6 = __shfl(h4[cg][2], src1), s7 = __shfl(h4[cg][3], src1);
            bf16x8 B2 = pk8(s0, s1, s2, s3, s4, s5, s6, s7);
            f32x4 z4 = {0.f, 0.f, 0.f, 0.f};
            f32x4 xm = __builtin_amdgcn_mfma_f32_16x16x32_bf16(A2, B2, z4, 0, 0, 0);

            // node partials: tuple row j = q*4+r -> node row g+j (private region)
            int rb = g + q * 4, col = cg * 16 + m;
            part[w][rb + 0][col] += xm[0];
            part[w][rb + 1][col] += xm[1];
            part[w][rb + 2][col] += xm[2];
            part[w][rb + 3][col] += xm[3];

            // X2 (block mean) + X1 (diag row 0) -> LDS bf16
            float ps = xm[0] + xm[1] + xm[2] + xm[3];
            ps += __shfl_xor(ps, 16);
            ps += __shfl_xor(ps, 32);
            float x1 = __shfl(xm[0], m);
            if (q == 0) {
                x2x1[g][col]      = f2bf_rhu(ps * (1.f / 16.f));
                x2x1[g][64 + col] = f2bf_rhu(x1);
            }
        }

        if (pf) { xa = nxa; xb = nxb; xc = nxc; xd = nxd; cw = ncw; }
    }
    __syncthreads();

    // fused Y matmul: Y[root0+..] = [X2|X1](16x128) @ W1ab + b1; wave w -> cols 16w..
    {
        float bvy = b1[w * 16 + m];
        f32x4 c = {bvy, bvy, bvy, bvy};
        const bf16x8* brow = (const bf16x8*)(WabT + (size_t)(w * 16 + m) * 128);
#pragma unroll
        for (int kh = 0; kh < 4; kh++) {
            bf16x8 a = *(const bf16x8*)&x2x1[m][kh * 32 + q * 8];
            c = __builtin_amdgcn_mfma_f32_16x16x32_bf16(a, brow[kh * 4 + q], c, 0, 0, 0);
        }
#pragma unroll
        for (int r = 0; r < 4; r++) {
            int row = root0 + q * 4 + r;
            if (row < R) Y[(size_t)row * 64 + w * 16 + m] = c[r];
        }
    }

    // merge 4 private regions -> Qpart
    float* qp = Qpart + (size_t)grp * (PROWS * 64);
    for (int idx = tid; idx < PROWS * 64; idx += 256) {
        int r = idx >> 6, col = idx & 63;
        qp[idx] = part[0][r][col] + part[1][r][col] + part[2][r][col] + part[3][r][col];
    }
}

// ---- K_linz: Z[N,64] = Qavg @ W1c (gathers <=2 Qpart regions per node) ----
__global__ __launch_bounds__(256) void k_linz(
    const float* __restrict__ Qpart, const unsigned short* __restrict__ WcT,
    float* __restrict__ Z, int R, int N)
{
    int tid = threadIdx.x, lane = tid & 63, w = tid >> 6, m = lane & 15, q = lane >> 4;
    int row0 = blockIdx.x * 16;
    int n = row0 + m;
    float inv = 0.f;
    int gLo = 0, gHi = -1;
    if (n < N) {
        int lo = n - (S - 1); if (lo < 0) lo = 0;
        int hi = (n < R - 1) ? n : (R - 1);
        inv = 1.f / (float)(hi - lo + 1);
        gLo = lo >> 4; gHi = hi >> 4;
    }
    f32x4 c = {0.f, 0.f, 0.f, 0.f};
    const bf16x8* brow = (const bf16x8*)(WcT + (size_t)(w * 16 + m) * 64);
#pragma unroll
    for (int kh = 0; kh < 2; kh++) {
        int k0 = kh * 32 + q * 8;
        float4 u = {0.f, 0.f, 0.f, 0.f}, v = {0.f, 0.f, 0.f, 0.f};
        for (int g = gLo; g <= gHi; g++) {
            const float* src = Qpart + ((size_t)g * PROWS + (n - g * 16)) * 64 + k0;
            float4 uu = *(const float4*)src, vv = *(const float4*)(src + 4);
            u.x += uu.x; u.y += uu.y; u.z += uu.z; u.w += uu.w;
            v.x += vv.x; v.y += vv.y; v.z += vv.z; v.w += vv.w;
        }
        bf16x8 a = pk8(u.x * inv, u.y * inv, u.z * inv, u.w * inv,
                       v.x * inv, v.y * inv, v.z * inv, v.w * inv);
        c = __builtin_amdgcn_mfma_f32_16x16x32_bf16(a, brow[kh * 4 + q], c, 0, 0, 0);
    }
#pragma unroll
    for (int r = 0; r < 4; r++) {
        int row = row0 + q * 4 + r;
        if (row < N) Z[(size_t)row * 64 + w * 16 + m] = c[r];
    }
}

// ---- K_out: out[i*16+j] = Y[i] + Z[i+j] ----
__global__ __launch_bounds__(256) void k_out(
    const float* __restrict__ Y, const float* __restrict__ Z,
    float4* __restrict__ out, int M)
{
    int idx = blockIdx.x * 256 + threadIdx.x;
    if (idx >= M * (D / 4)) return;
    int t = idx >> 4, d4 = idx & 15;
    int i = t >> 4, j = t & 15;
    int n = i + j;
    const float4* Y4 = (const float4*)Y;
    const float4* Z4 = (const float4*)Z;
    float4 a = Y4[(size_t)i * 16 + d4];
    float4 b = Z4[(size_t)n * 16 + d4];
    float4 o;
    o.x = a.x + b.x; o.y = a.y + b.y; o.z = a.z + b.z; o.w = a.w + b.w;
    out[idx] = o;
}

extern "C" void kernel_launch(void* const* d_in, const int* in_sizes, int n_in,
                              void* d_out, int out_size, void* d_ws, size_t ws_size,
                              hipStream_t stream) {
    (void)n_in; (void)out_size; (void)ws_size;
    const float* X  = (const float*)d_in[0];
    const float* W0 = (const float*)d_in[1];
    const float* b0 = (const float*)d_in[2];
    const float* W1 = (const float*)d_in[3];
    const float* b1 = (const float*)d_in[4];
    const int* msg_tgt = (const int*)d_in[8];
    const int* msg_src = (const int*)d_in[9];
    const int M = in_sizes[5];           // rootid size = R*S
    const int R = in_sizes[7];           // diag_tuple size
    const int E = in_sizes[8];           // number of tuple-level messages
    const int N = R + S - 1;

    char* p = (char*)d_ws;
    unsigned long long* adjcnt = (unsigned long long*)p; p += (size_t)M * 8;
    float* Y    = (float*)p;             p += (size_t)R * 64 * 4;
    float* Z    = (float*)p;             p += (size_t)N * 64 * 4;
    unsigned short* W0T  = (unsigned short*)p; p += (size_t)4096 * 2;
    unsigned short* WabT = (unsigned short*)p; p += (size_t)8192 * 2;
    unsigned short* WcT  = (unsigned short*)p; p += (size_t)4096 * 2;

    // Qpart lives in d_out (written by k_root, consumed by k_linz, then k_out
    // fully overwrites d_out). NG*31*64*4 ~ 14.9 MB << out bytes.
    int NG = (R + G - 1) / G;
    float* Qpart = (float*)d_out;

    hipMemsetAsync(adjcnt, 0, (size_t)M * 8, stream);
    k_prep<<<64, 256, 0, stream>>>(W0, W1, W0T, WabT, WcT);
    k_counts<<<(E + 255) / 256, 256, 0, stream>>>(msg_tgt, msg_src, adjcnt, E);
    k_root<<<NG, 256, 0, stream>>>(X, b0, W0T, adjcnt, WabT, b1, Y, Qpart, R);
    int NB = (N + 15) / 16;
    k_linz<<<NB, 256, 0, stream>>>(Qpart, WcT, Z, R, N);
    k_out<<<(M * (D / 4) + 255) / 256, 256, 0, stream>>>(Y, Z, (float4*)d_out, M);
}